// Round 5
// baseline (40.567 us; speedup 1.0000x reference)
//
#include <hip/hip_runtime.h>

#define S_TOT 2048
#define B_SZ  32
#define I_SZ  256
#define O_SZ  80

typedef _Float16 f16x8 __attribute__((ext_vector_type(8)));
typedef float    f32x4 __attribute__((ext_vector_type(4)));

// Flat-wave design: global wave gw = blockIdx.x*4 + (tid>>6); s = gw/5,
// o-chunk w = gw%5 (o in [16w,16w+16)). No LDS, no barrier: A-fragments are
// read straight from global with the SAME (lane,ks)->k map as the B
// fragments (lane (m,ks) holds k = kc*32+ks*8 .. +8), so MFMA dot products
// line up; L1/L2/L3 absorb the ~3x re-read of x across active waves.
// RAGGED-K: x pre-masked beyond in_size -> skip K-chunks >= kcmax (from
//   in_mask prefix-ones, wave-uniform).
// RAGGED-O: out_mask prefix-ones -> wave inactive iff out_mask[s][16w]==0:
//   write zeros, retire early (frees the SIMD slot). Partially-active
//   chunk: masked lanes skip W loads (b-frag zeroed, om=0 path exact).
__device__ __forceinline__ float ftanh(float v) {
  float e = __expf(2.0f * v);
  return 1.0f - __fdividef(2.0f, e + 1.0f);
}

__device__ __forceinline__ f16x8 cvt8(f32x4 lo, f32x4 hi) {
  f16x8 h;
  h[0] = (_Float16)lo[0]; h[1] = (_Float16)lo[1];
  h[2] = (_Float16)lo[2]; h[3] = (_Float16)lo[3];
  h[4] = (_Float16)hi[0]; h[5] = (_Float16)hi[1];
  h[6] = (_Float16)hi[2]; h[7] = (_Float16)hi[3];
  return h;
}

__global__ __launch_bounds__(256, 6) void dcell_kernel(
    const float* __restrict__ x,        // [S, 32, 256]
    const float* __restrict__ W,        // [S, 80, 256]
    const float* __restrict__ bias,     // [S, 80]
    const float* __restrict__ gamma,    // [S, 80]
    const float* __restrict__ beta,     // [S, 80]
    const float* __restrict__ in_mask,  // [S, 256]
    const float* __restrict__ out_mask, // [S, 80]
    float* __restrict__ out)            // [S, 32, 80]
{
  const int gw = blockIdx.x * 4 + (threadIdx.x >> 6);   // 0 .. S*5-1
  const int s  = gw / 5;
  const int w  = gw - s * 5;
  const int l  = threadIdx.x & 63;
  const int m  = l & 15;     // A row / B col within 16x16 tile
  const int ks = l >> 4;     // k-slice 0..3
  const int ob = w * 16;
  const int o  = ob + m;

  const float* omp = out_mask + (size_t)s * O_SZ;
  float* og = out + (size_t)s * (B_SZ * O_SZ) + o;

  if (omp[ob] == 0.0f) {
    // fully-masked o-chunk: output is exactly 0 (d_out is poisoned).
#pragma unroll
    for (int r = 0; r < 4; ++r) {
      int b0 = ks * 4 + r;
      og[(size_t)b0 * O_SZ]        = 0.f;
      og[(size_t)(b0 + 16) * O_SZ] = 0.f;
    }
    return;
  }
  const bool lane_act = (omp[o] != 0.0f);

  // active K-chunk count (wave-uniform; in_mask is prefix-ones)
  const float* im = in_mask + (size_t)s * I_SZ;
  float msum = im[0] + im[32] + im[64] + im[96] +
               im[128] + im[160] + im[192] + im[224];
  const int kcmax = (int)(msum + 0.5f);   // 1..8

  // per-lane global fragment pointers
  const float* xr0 = x + ((size_t)s * B_SZ + m) * I_SZ + ks * 8;   // b = m
  const float* xr1 = xr0 + 16 * I_SZ;                               // b = m+16
  const float* wr  = W + ((size_t)s * O_SZ + o) * I_SZ + ks * 8;

  f32x4 acc0 = {0.f, 0.f, 0.f, 0.f};
  f32x4 acc1 = {0.f, 0.f, 0.f, 0.f};
#pragma unroll
  for (int kc = 0; kc < 8; ++kc) {
    if (kc < kcmax) {
      f32x4 a0l = *(const f32x4*)(xr0 + kc * 32);
      f32x4 a0h = *(const f32x4*)(xr0 + kc * 32 + 4);
      f32x4 a1l = *(const f32x4*)(xr1 + kc * 32);
      f32x4 a1h = *(const f32x4*)(xr1 + kc * 32 + 4);
      f16x8 bb = {0, 0, 0, 0, 0, 0, 0, 0};
      if (lane_act) {
        f32x4 bl = *(const f32x4*)(wr + kc * 32);
        f32x4 bh = *(const f32x4*)(wr + kc * 32 + 4);
        bb = cvt8(bl, bh);
      }
      f16x8 a0 = cvt8(a0l, a0h);
      f16x8 a1 = cvt8(a1l, a1h);
      acc0 = __builtin_amdgcn_mfma_f32_16x16x32_f16(a0, bb, acc0, 0, 0, 0);
      acc1 = __builtin_amdgcn_mfma_f32_16x16x32_f16(a1, bb, acc1, 0, 0, 0);
    }
  }

  // ---- epilogue: bias, tanh, BatchNorm over b (in-register), mask, store.
  // C layout (m89): col = lane&15, row = (lane>>4)*4 + reg.
  const float bv = bias[s * O_SZ + o];
  float t0[4], t1[4];
  float sum = 0.f;
#pragma unroll
  for (int r = 0; r < 4; ++r) {
    t0[r] = ftanh(acc0[r] + bv);
    t1[r] = ftanh(acc1[r] + bv);
    sum += t0[r] + t1[r];
  }
  sum += __shfl_xor(sum, 16);   // exchanges ks bits only -> same o column
  sum += __shfl_xor(sum, 32);
  const float mean = sum * (1.0f / 32.0f);

  float vs = 0.f;
#pragma unroll
  for (int r = 0; r < 4; ++r) {
    float d0 = t0[r] - mean, d1 = t1[r] - mean;
    vs += d0 * d0 + d1 * d1;
  }
  vs += __shfl_xor(vs, 16);
  vs += __shfl_xor(vs, 32);
  const float rstd = rsqrtf(vs * (1.0f / 32.0f) + 1e-5f);

  const float g  = gamma[s * O_SZ + o] * rstd;
  const float be = beta[s * O_SZ + o];
  const float om = omp[o];

#pragma unroll
  for (int r = 0; r < 4; ++r) {
    int b0 = ks * 4 + r;
    og[(size_t)b0 * O_SZ]        = ((t0[r] - mean) * g + be) * om;
    og[(size_t)(b0 + 16) * O_SZ] = ((t1[r] - mean) * g + be) * om;
  }
}

extern "C" void kernel_launch(void* const* d_in, const int* in_sizes, int n_in,
                              void* d_out, int out_size, void* d_ws, size_t ws_size,
                              hipStream_t stream) {
  const float* x        = (const float*)d_in[0];
  const float* W        = (const float*)d_in[1];
  const float* bias     = (const float*)d_in[2];
  const float* gamma    = (const float*)d_in[3];
  const float* beta     = (const float*)d_in[4];
  const float* in_mask  = (const float*)d_in[5];
  const float* out_mask = (const float*)d_in[6];
  float* out = (float*)d_out;

  // S*5 waves total, 4 waves per 256-thread block
  dcell_kernel<<<dim3((S_TOT * 5) / 4), dim3(256), 0, stream>>>(
      x, W, bias, gamma, beta, in_mask, out_mask, out);
}